// Round 10
// baseline (141.389 us; speedup 1.0000x reference)
//
#include <hip/hip_runtime.h>
#include <math.h>

// out [1, 128, N] f32:
//   rows   0.. 63 : pdf^T               (pdf [N,64] row-major)
//   rows  64.. 95 : te[c] broadcast     (timestep embedding, single vector)
//   rows  96..127 : mask[p] ? me1[c] : me0[c]
//
// ws layout: te[0..31], me0[32..63], me1[64..95]
//
// R9 = R8 cache policy (temporal loads, scalar NT stores, m204 XCD swizzle)
//      with 512-pt tiles x 1024 threads: per-row write segment 1KB -> 2KB.
//      LDS 64x512 f32 = exactly 128 KiB (R2-proven size) with R2's verified
//      XOR swizzle (no padding). 1 block/CU = 16 waves/CU.

#define HALF 32
#define PTS 512   // points per tile

typedef float v4f __attribute__((ext_vector_type(4)));

__global__ void embed_small_kernel(const float* __restrict__ t,
                                   const float* __restrict__ ef_w1, const float* __restrict__ ef_b1,
                                   const float* __restrict__ ef_w2, const float* __restrict__ ef_b2,
                                   const float* __restrict__ em_w1, const float* __restrict__ em_b1,
                                   const float* __restrict__ em_w2, const float* __restrict__ em_b2,
                                   float* __restrict__ ws) {
    __shared__ float h[3][64];
    const int tid = threadIdx.x;
    const float log_scale = 0.2970934777f;  // ln(10000)/31

    if (tid < 192) {
        const int v = tid >> 6;      // 0: sin-emb(t)->ef, 1: sin-emb(0)->em, 2: sin-emb(1)->em
        const int j = tid & 63;
        const float val = (v == 0) ? t[0] : (float)(v - 1);
        const float* w1 = (v == 0) ? ef_w1 : em_w1;
        const float* b1 = (v == 0) ? ef_b1 : em_b1;
        float acc = b1[j];
        for (int k = 0; k < HALF; ++k) {
            float f = expf(-(float)k * log_scale);
            float ang = val * f;
            float s, c;
            sincosf(ang, &s, &c);
            acc += s * w1[j * 64 + k] + c * w1[j * 64 + HALF + k];
        }
        h[v][j] = (acc > 0.0f) ? acc : 0.1f * acc;  // LeakyReLU(0.1)
    }
    __syncthreads();
    if (tid < 96) {
        const int v = tid >> 5;
        const int c = tid & 31;
        const float* w2 = (v == 0) ? ef_w2 : em_w2;
        const float* b2 = (v == 0) ? ef_b2 : em_b2;
        float acc = b2[c];
        for (int j = 0; j < 64; ++j) acc += h[v][j] * w2[c * 64 + j];
        ws[v * 32 + c] = acc;
    }
}

__global__ __launch_bounds__(1024) void pvcnn_cond_kernel(
        const float* __restrict__ pdf,
        const int* __restrict__ mask,
        const float* __restrict__ ws,
        float* __restrict__ out,
        int N) {
    __shared__ float tile[64 * PTS];   // exactly 128 KiB, channel-major, XOR-swizzled

    const int tid = threadIdx.x;

    // ---- bijective XCD-contiguous swizzle (m204) ----
    const int nwg = gridDim.x;
    const int q   = nwg >> 3;
    const int r8  = nwg & 7;
    const int xcd = blockIdx.x & 7;
    const int j8  = blockIdx.x >> 3;
    const int bid = (xcd < r8 ? xcd * (q + 1) : r8 * (q + 1) + (xcd - r8) * q) + j8;

    const long long p0 = (long long)bid * PTS;
    const bool full = (p0 + PTS <= (long long)N);

    // ---- phase 1: pdf tile -> LDS channel-major (TEMPORAL float4 loads) ----
    // f in [0,8192): p = f>>4 (point 0..511), k = f&15 (chan block: chans 4k..4k+3)
    // swizzled point index: p ^ ((k&7)<<2)  (R2-verified: writes 2-way free)
    if (full) {
        const v4f* src = (const v4f*)(pdf + p0 * 64);
        #pragma unroll
        for (int it = 0; it < 8; ++it) {
            const int f = tid + it * 1024;
            const int p = f >> 4;
            const int k = f & 15;
            const v4f v = src[f];               // temporal: L3 keeps pdf
            const int b = (k << 2) * PTS + (p ^ ((k & 7) << 2));
            tile[b + 0 * PTS] = v.x;
            tile[b + 1 * PTS] = v.y;
            tile[b + 2 * PTS] = v.z;
            tile[b + 3 * PTS] = v.w;
        }
    } else {
        #pragma unroll
        for (int it = 0; it < 8; ++it) {
            const int f = tid + it * 1024;
            const int p = f >> 4;
            const int k = f & 15;
            v4f v = {0.f, 0.f, 0.f, 0.f};
            if (p0 + p < (long long)N)
                v = ((const v4f*)(pdf + (p0 + p) * 64))[k];
            const int b = (k << 2) * PTS + (p ^ ((k & 7) << 2));
            tile[b + 0 * PTS] = v.x;
            tile[b + 1 * PTS] = v.y;
            tile[b + 2 * PTS] = v.z;
            tile[b + 3 * PTS] = v.w;
        }
    }

    // phase-2 assignment: c = column within tile (0..511), rg = row parity (0..1)
    const int c  = tid & 511;
    const int rg = tid >> 9;
    const long long col = p0 + c;
    const bool cok = (col < (long long)N);

    int mval = 0;
    if (cok) mval = mask[col];          // temporal, coalesced

    __syncthreads();

    // ---- phase 2: 128 rows; r = rg + 2*rr -> 2 adjacent rows x 2KB per instant ----
    if (full) {
        #pragma unroll
        for (int rr = 0; rr < 64; ++rr) {
            const int r = rg + 2 * rr;
            float v;
            if (rr < 32) {                    // rows 0..63: transpose from LDS
                v = tile[r * PTS + (c ^ (((r >> 2) & 7) << 2))];
            } else if (rr < 48) {             // rows 64..95: te broadcast
                v = ws[r - 64];               // uniform scalar load
            } else {                          // rows 96..127: mask embedding
                v = mval ? ws[64 + (r - 96)] : ws[32 + (r - 96)];
            }
            __builtin_nontemporal_store(v, out + (long long)r * N + col);
        }
    } else if (cok) {
        for (int rr = 0; rr < 64; ++rr) {
            const int r = rg + 2 * rr;
            float v;
            if (rr < 32) {
                v = tile[r * PTS + (c ^ (((r >> 2) & 7) << 2))];
            } else if (rr < 48) {
                v = ws[r - 64];
            } else {
                v = mval ? ws[64 + (r - 96)] : ws[32 + (r - 96)];
            }
            __builtin_nontemporal_store(v, out + (long long)r * N + col);
        }
    }
}

extern "C" void kernel_launch(void* const* d_in, const int* in_sizes, int n_in,
                              void* d_out, int out_size, void* d_ws, size_t ws_size,
                              hipStream_t stream) {
    // 0: inputs [1,6,N]; 1: t [1]; 2: mask [N] i32; 3: pdf [N,64];
    // 4..7: ef_w1,ef_b1,ef_w2,ef_b2; 8..11: em_w1,em_b1,em_w2,em_b2
    const float* t     = (const float*)d_in[1];
    const int*   mask  = (const int*)d_in[2];
    const float* pdf   = (const float*)d_in[3];
    const float* ef_w1 = (const float*)d_in[4];
    const float* ef_b1 = (const float*)d_in[5];
    const float* ef_w2 = (const float*)d_in[6];
    const float* ef_b2 = (const float*)d_in[7];
    const float* em_w1 = (const float*)d_in[8];
    const float* em_b1 = (const float*)d_in[9];
    const float* em_w2 = (const float*)d_in[10];
    const float* em_b2 = (const float*)d_in[11];

    float* out = (float*)d_out;
    float* ws  = (float*)d_ws;
    const int N = in_sizes[2];

    embed_small_kernel<<<1, 192, 0, stream>>>(t, ef_w1, ef_b1, ef_w2, ef_b2,
                                              em_w1, em_b1, em_w2, em_b2, ws);

    const int nblocks = (N + PTS - 1) / PTS;
    pvcnn_cond_kernel<<<nblocks, 1024, 0, stream>>>(pdf, mask, ws, out, N);
}

// Round 11
// 130.467 us; speedup vs baseline: 1.0837x; 1.0837x over previous
//
#include <hip/hip_runtime.h>
#include <math.h>

// out [1, 128, N] f32:
//   rows   0.. 63 : pdf^T               (pdf [N,64] row-major)
//   rows  64.. 95 : te[c] broadcast     (timestep embedding, single vector)
//   rows  96..127 : mask[p] ? me1[c] : me0[c]
//
// ws layout: te[0..31], me0[32..63], me1[64..95]
//
// R10 = revert to R8 (best: 130.8 us):
//   temporal loads (pdf/mask), scalar NT stores, m204 XCD swizzle,
//   256-pt tiles x 1024 threads, per-row 1KB contiguous write segments,
//   LDS [64][257] = 64.3KB -> 2 blocks/CU = 32 waves/CU.
// 5.90 TB/s logical = 94% of m13 copy ceiling (6.29 TB/s). Roofline candidate.

#define HALF 32
#define PTS 256   // points per tile

typedef float v4f __attribute__((ext_vector_type(4)));

__global__ void embed_small_kernel(const float* __restrict__ t,
                                   const float* __restrict__ ef_w1, const float* __restrict__ ef_b1,
                                   const float* __restrict__ ef_w2, const float* __restrict__ ef_b2,
                                   const float* __restrict__ em_w1, const float* __restrict__ em_b1,
                                   const float* __restrict__ em_w2, const float* __restrict__ em_b2,
                                   float* __restrict__ ws) {
    __shared__ float h[3][64];
    const int tid = threadIdx.x;
    const float log_scale = 0.2970934777f;  // ln(10000)/31

    if (tid < 192) {
        const int v = tid >> 6;      // 0: sin-emb(t)->ef, 1: sin-emb(0)->em, 2: sin-emb(1)->em
        const int j = tid & 63;
        const float val = (v == 0) ? t[0] : (float)(v - 1);
        const float* w1 = (v == 0) ? ef_w1 : em_w1;
        const float* b1 = (v == 0) ? ef_b1 : em_b1;
        float acc = b1[j];
        for (int k = 0; k < HALF; ++k) {
            float f = expf(-(float)k * log_scale);
            float ang = val * f;
            float s, c;
            sincosf(ang, &s, &c);
            acc += s * w1[j * 64 + k] + c * w1[j * 64 + HALF + k];
        }
        h[v][j] = (acc > 0.0f) ? acc : 0.1f * acc;  // LeakyReLU(0.1)
    }
    __syncthreads();
    if (tid < 96) {
        const int v = tid >> 5;
        const int c = tid & 31;
        const float* w2 = (v == 0) ? ef_w2 : em_w2;
        const float* b2 = (v == 0) ? ef_b2 : em_b2;
        float acc = b2[c];
        for (int j = 0; j < 64; ++j) acc += h[v][j] * w2[c * 64 + j];
        ws[v * 32 + c] = acc;
    }
}

__global__ __launch_bounds__(1024) void pvcnn_cond_kernel(
        const float* __restrict__ pdf,
        const int* __restrict__ mask,
        const float* __restrict__ ws,
        float* __restrict__ out,
        int N) {
    __shared__ float tile[64 * 257];   // channel-major, row stride 257 (pad +1)
    __shared__ float emb[96];

    const int tid = threadIdx.x;

    // ---- bijective XCD-contiguous swizzle (m204) ----
    const int nwg = gridDim.x;
    const int q   = nwg >> 3;
    const int r8  = nwg & 7;
    const int xcd = blockIdx.x & 7;
    const int j8  = blockIdx.x >> 3;
    const int bid = (xcd < r8 ? xcd * (q + 1) : r8 * (q + 1) + (xcd - r8) * q) + j8;

    const long long p0 = (long long)bid * PTS;
    const bool full = (p0 + PTS <= (long long)N);

    if (tid < 96) emb[tid] = ws[tid];

    // ---- phase 1: pdf tile -> LDS channel-major (TEMPORAL float4 loads) ----
    // f in [0,4096): p = f>>4 (point 0..255), qq = f&15 (chan block), chans 4qq..4qq+3.
    // LDS bank for write: (4qq + d + p) mod 32 -> 2-way (free).
    if (full) {
        const v4f* src = (const v4f*)(pdf + p0 * 64);
        #pragma unroll
        for (int it = 0; it < 4; ++it) {
            const int f = tid + it * 1024;
            const int p = f >> 4;
            const int qq = f & 15;
            const v4f v = src[f];               // temporal: L2/L3 path
            const int b = (4 * qq) * 257 + p;
            tile[b + 0 * 257] = v.x;
            tile[b + 1 * 257] = v.y;
            tile[b + 2 * 257] = v.z;
            tile[b + 3 * 257] = v.w;
        }
    } else {
        #pragma unroll
        for (int it = 0; it < 4; ++it) {
            const int f = tid + it * 1024;
            const int p = f >> 4;
            const int qq = f & 15;
            v4f v = {0.f, 0.f, 0.f, 0.f};
            if (p0 + p < (long long)N)
                v = ((const v4f*)(pdf + (p0 + p) * 64))[qq];
            const int b = (4 * qq) * 257 + p;
            tile[b + 0 * 257] = v.x;
            tile[b + 1 * 257] = v.y;
            tile[b + 2 * 257] = v.z;
            tile[b + 3 * 257] = v.w;
        }
    }

    // phase-2 assignment: rg = row-group (0..3), c = column within tile (0..255)
    const int c  = tid & 255;
    const int rg = tid >> 8;
    const long long col = p0 + c;
    const bool cok = (col < (long long)N);

    int mval = 0;
    if (cok) mval = mask[col];          // temporal, coalesced 1KB per row-group

    __syncthreads();

    // ---- phase 2: 128 rows; row-group rg writes rows r = rg + 4*rr ----
    // per wave-instr: 256B contiguous; 4 waves of a row-group -> 1KB/row/block.
    if (full) {
        #pragma unroll
        for (int rr = 0; rr < 32; ++rr) {
            const int r = rg + 4 * rr;
            float v;
            if (rr < 16) {                    // rows 0..63: transpose from LDS
                v = tile[r * 257 + c];        // bank (r+c)%32 -> 2-way free
            } else if (rr < 24) {             // rows 64..95: te broadcast
                v = emb[r - 64];
            } else {                          // rows 96..127: mask embedding
                v = mval ? emb[64 + (r - 96)] : emb[32 + (r - 96)];
            }
            __builtin_nontemporal_store(v, out + (long long)r * N + col);
        }
    } else if (cok) {
        for (int rr = 0; rr < 32; ++rr) {
            const int r = rg + 4 * rr;
            float v;
            if (rr < 16) {
                v = tile[r * 257 + c];
            } else if (rr < 24) {
                v = emb[r - 64];
            } else {
                v = mval ? emb[64 + (r - 96)] : emb[32 + (r - 96)];
            }
            __builtin_nontemporal_store(v, out + (long long)r * N + col);
        }
    }
}

extern "C" void kernel_launch(void* const* d_in, const int* in_sizes, int n_in,
                              void* d_out, int out_size, void* d_ws, size_t ws_size,
                              hipStream_t stream) {
    // 0: inputs [1,6,N]; 1: t [1]; 2: mask [N] i32; 3: pdf [N,64];
    // 4..7: ef_w1,ef_b1,ef_w2,ef_b2; 8..11: em_w1,em_b1,em_w2,em_b2
    const float* t     = (const float*)d_in[1];
    const int*   mask  = (const int*)d_in[2];
    const float* pdf   = (const float*)d_in[3];
    const float* ef_w1 = (const float*)d_in[4];
    const float* ef_b1 = (const float*)d_in[5];
    const float* ef_w2 = (const float*)d_in[6];
    const float* ef_b2 = (const float*)d_in[7];
    const float* em_w1 = (const float*)d_in[8];
    const float* em_b1 = (const float*)d_in[9];
    const float* em_w2 = (const float*)d_in[10];
    const float* em_b2 = (const float*)d_in[11];

    float* out = (float*)d_out;
    float* ws  = (float*)d_ws;
    const int N = in_sizes[2];

    embed_small_kernel<<<1, 192, 0, stream>>>(t, ef_w1, ef_b1, ef_w2, ef_b2,
                                              em_w1, em_b1, em_w2, em_b2, ws);

    const int nblocks = (N + PTS - 1) / PTS;
    pvcnn_cond_kernel<<<nblocks, 1024, 0, stream>>>(pdf, mask, ws, out, N);
}